// Round 1
// baseline (305.101 us; speedup 1.0000x reference)
//
#include <hip/hip_runtime.h>
#include <math.h>

#define EPS 1e-5f

__device__ __forceinline__ float sigmoidf_(float v){ return 1.0f/(1.0f+expf(-v)); }

// ---------------- K1: per-(bg,c) row sums, col sums, total, corners ----------------
__global__ __launch_bounds__(256) void k1_rowcol(const float* __restrict__ x,
    float* __restrict__ rs, float* __restrict__ cs, float* __restrict__ chansum,
    float* __restrict__ corners)
{
    const int bgc = blockIdx.x;           // b*512 + C  == bg*16 + c
    const int tid = threadIdx.x;
    __shared__ float srow[64];
    __shared__ float scol[64];
    if (tid < 64) scol[tid] = 0.0f;
    __syncthreads();
    const float4* x4 = (const float4*)(x + (size_t)bgc * 4096);
    float c0=0.f,c1=0.f,c2=0.f,c3=0.f;
    #pragma unroll
    for (int it=0; it<4; ++it){
        int f = it*256 + tid;
        float4 v = x4[f];
        int i = f >> 4;
        float rsum = v.x+v.y+v.z+v.w;
        rsum += __shfl_xor(rsum, 1);
        rsum += __shfl_xor(rsum, 2);
        rsum += __shfl_xor(rsum, 4);
        rsum += __shfl_xor(rsum, 8);
        if ((tid & 15)==0) srow[i] = rsum;
        c0+=v.x; c1+=v.y; c2+=v.z; c3+=v.w;
    }
    int jb = (tid & 15)*4;
    atomicAdd(&scol[jb+0], c0);
    atomicAdd(&scol[jb+1], c1);
    atomicAdd(&scol[jb+2], c2);
    atomicAdd(&scol[jb+3], c3);
    __syncthreads();
    if (tid < 64){
        float v = srow[tid];
        float t = v;
        t += __shfl_xor(t,1); t += __shfl_xor(t,2); t += __shfl_xor(t,4);
        t += __shfl_xor(t,8); t += __shfl_xor(t,16); t += __shfl_xor(t,32);
        if (tid==0) chansum[bgc] = t;
        rs[bgc*64 + tid] = v;
        cs[bgc*64 + tid] = scol[tid];
    }
    if (tid == 0){
        const float* xb = x + (size_t)bgc*4096;
        corners[bgc*4+0] = xb[0];        // (row0,col0)
        corners[bgc*4+1] = xb[63];       // (row0,col63)
        corners[bgc*4+2] = xb[63*64];    // (row63,col0)
        corners[bgc*4+3] = xb[4095];     // (row63,col63)
    }
}

// ---------------- K0: weff = sum_o a11[o]*w3[o], bconst = sum_o a11[o]*b3[o]; a11 = softmax(gn_b) ----------------
__global__ __launch_bounds__(256) void k0_weff(const float* __restrict__ w3, const float* __restrict__ b3,
    const float* __restrict__ gn_b, float* __restrict__ weff, float* __restrict__ bconst)
{
    __shared__ float a11[16];
    int tid = threadIdx.x;
    if (tid==0){
        float m = gn_b[0];
        for (int i=1;i<16;++i) m = fmaxf(m, gn_b[i]);
        float s=0.f, e[16];
        for (int i=0;i<16;++i){ e[i]=expf(gn_b[i]-m); s+=e[i]; }
        for (int i=0;i<16;++i) a11[i]=e[i]/s;
    }
    __syncthreads();
    if (tid<144){
        float acc=0.f;
        for (int o=0;o<16;++o) acc += a11[o]*w3[o*144+tid];
        weff[tid]=acc;
    }
    if (tid==160){
        float acc=0.f;
        for (int o=0;o<16;++o) acc += a11[o]*b3[o];
        bconst[0]=acc;
    }
}

// ---------------- K2: gates sh/sw: sigmoid(w1 @ [rowmean; colmean] + b1) ----------------
__global__ __launch_bounds__(128) void k2_gates(const float* __restrict__ rs, const float* __restrict__ cs,
    const float* __restrict__ w1, const float* __restrict__ b1,
    float* __restrict__ sh, float* __restrict__ sw)
{
    int bg = blockIdx.x, l = threadIdx.x;
    __shared__ float w1s[256], b1s[16];
    w1s[l] = w1[l]; w1s[l+128] = w1[l+128];
    if (l<16) b1s[l]=b1[l];
    __syncthreads();
    float cat[16];
    bool isrow = l < 64;
    int p = isrow ? l : (l-64);
    const float* src = isrow ? rs : cs;
    #pragma unroll
    for (int c=0;c<16;++c) cat[c] = src[bg*1024 + c*64 + p]*(1.0f/64.0f);
    #pragma unroll
    for (int o=0;o<16;++o){
        float acc = b1s[o];
        #pragma unroll
        for (int c=0;c<16;++c) acc += w1s[o*16+c]*cat[c];
        float sg = sigmoidf_(acc);
        if (isrow) sh[bg*1024 + o*64 + p] = sg;
        else       sw[bg*1024 + o*64 + p] = sg;
    }
}

// ---------------- SE block (used for se1 and se2): 512 -> relu(32) -> sigmoid(512) ----------------
__global__ __launch_bounds__(512) void k_se(const float* __restrict__ pin, float scale,
    const float* __restrict__ wa, const float* __restrict__ ba,
    const float* __restrict__ wb, const float* __restrict__ bb,
    float* __restrict__ seout)
{
    int b = blockIdx.x, tid = threadIdx.x;
    __shared__ float pv[512];
    __shared__ float hdn[32];
    pv[tid] = pin[b*512+tid]*scale;
    __syncthreads();
    if (tid<32){
        float acc = ba[tid];
        const float* wr = wa + tid*512;
        for (int k=0;k<512;++k) acc += wr[k]*pv[k];
        hdn[tid] = fmaxf(acc, 0.0f);
    }
    __syncthreads();
    float acc = bb[tid];
    const float* wr = wb + tid*32;
    #pragma unroll
    for (int k=0;k<32;++k) acc += wr[k]*hdn[k];
    seout[b*512+tid] = sigmoidf_(acc);
}

// ---------------- K3: instance-norm stats of x1 = gx*sh_i*sw_j ----------------
__global__ __launch_bounds__(256) void k3_stats(const float* __restrict__ x,
    const float* __restrict__ sh, const float* __restrict__ sw,
    float* __restrict__ mu, float* __restrict__ rstd)
{
    int bgc = blockIdx.x, tid = threadIdx.x;
    int bg = bgc >> 4, c = bgc & 15;
    __shared__ float shv[64], swv[64];
    __shared__ float r1[4], r2[4];
    if (tid<64) shv[tid] = sh[bg*1024 + c*64 + tid];
    else if (tid<128) swv[tid-64] = sw[bg*1024 + c*64 + (tid-64)];
    __syncthreads();
    const float4* x4 = (const float4*)(x + (size_t)bgc*4096);
    float s1=0.f, s2=0.f;
    int jb = (tid&15)*4;
    #pragma unroll
    for (int it=0; it<4; ++it){
        int f = it*256+tid;
        float4 v = x4[f];
        int i = f>>4;
        float si = shv[i];
        float a0 = v.x*si*swv[jb+0];
        float a1 = v.y*si*swv[jb+1];
        float a2 = v.z*si*swv[jb+2];
        float a3 = v.w*si*swv[jb+3];
        s1 += a0+a1+a2+a3;
        s2 += a0*a0+a1*a1+a2*a2+a3*a3;
    }
    #pragma unroll
    for (int m=1; m<64; m<<=1){ s1 += __shfl_xor(s1,m); s2 += __shfl_xor(s2,m); }
    int lane = tid&63, wid = tid>>6;
    if (lane==0){ r1[wid]=s1; r2[wid]=s2; }
    __syncthreads();
    if (tid==0){
        float S1 = r1[0]+r1[1]+r1[2]+r1[3];
        float S2 = r2[0]+r2[1]+r2[2]+r2[3];
        float m = S1*(1.0f/4096.0f);
        float var = S2*(1.0f/4096.0f) - m*m;
        mu[bgc]=m;
        rstd[bgc]=rsqrtf(var+EPS);
    }
}

// ---------------- K4: analytic mean(x2) -> a21 -> alpha, cst ----------------
__global__ __launch_bounds__(256) void k4_a21(const float* __restrict__ w3, const float* __restrict__ b3,
    const float* __restrict__ gn_w, const float* __restrict__ gn_b,
    const float* __restrict__ rs, const float* __restrict__ cs,
    const float* __restrict__ chansum, const float* __restrict__ corners,
    const float* __restrict__ mu, const float* __restrict__ rstd,
    const float* __restrict__ bconst,
    float* __restrict__ alpha, float* __restrict__ cst)
{
    int bg = blockIdx.x, tid = threadIdx.x;
    __shared__ float w3s[2304];
    __shared__ float regs[144];
    __shared__ float m2[16];
    __shared__ float a21[16];
    #pragma unroll
    for (int k=0;k<9;++k) w3s[tid + k*256] = w3[tid + k*256];
    if (tid < 144){
        int c = tid/9, k = tid - c*9, ky = k/3, kx = k - ky*3;
        int bgc = bg*16 + c;
        float r = chansum[bgc];
        if (ky==0) r -= rs[bgc*64+63];   // shift u=-1 excludes row 63
        if (ky==2) r -= rs[bgc*64+0];    // shift u=+1 excludes row 0
        if (kx==0) r -= cs[bgc*64+63];
        if (kx==2) r -= cs[bgc*64+0];
        if (ky!=1 && kx!=1) r += corners[bgc*4 + ((ky==0)?2:0) + ((kx==0)?1:0)];
        regs[tid] = r;
    }
    __syncthreads();
    if (tid<16){
        float s=0.f;
        const float* wo = w3s + tid*144;
        for (int q=0;q<144;++q) s += wo[q]*regs[q];
        m2[tid] = b3[tid] + s*(1.0f/4096.0f);
    }
    __syncthreads();
    if (tid==0){
        float m = m2[0];
        for (int i=1;i<16;++i) m = fmaxf(m, m2[i]);
        float s=0.f, e[16];
        for (int i=0;i<16;++i){ e[i]=expf(m2[i]-m); s+=e[i]; }
        for (int i=0;i<16;++i) a21[i] = e[i]/s;
    }
    __syncthreads();
    if (tid<16){
        int bgc = bg*16+tid;
        alpha[bgc] = a21[tid]*gn_w[tid]*rstd[bgc];
    }
    if (tid==0){
        float cv = bconst[0];
        for (int c2=0;c2<16;++c2){
            int bgc = bg*16+c2;
            cv += a21[c2]*(gn_b[c2] - gn_w[c2]*rstd[bgc]*mu[bgc]);
        }
        cst[bg] = cv;
    }
}

// ---------------- K5: wv = conv(gx,weff) + sum_c alpha*sh*sw*gx + cst ; sig=sigmoid(wv); p2 means ----------------
__global__ __launch_bounds__(256) void k5_wv(const float* __restrict__ x,
    const float* __restrict__ sh, const float* __restrict__ sw,
    const float* __restrict__ alpha, const float* __restrict__ cst,
    const float* __restrict__ weff,
    const float* __restrict__ se1, const float* __restrict__ chansum,
    const float* __restrict__ gamma,
    float* __restrict__ sigbuf, float* __restrict__ p2)
{
    int bg = blockIdx.x, tid = threadIdx.x;
    __shared__ float ldsx[16*10*66];   // [c][row 0..9][col 0..65], cols padded with zeros
    __shared__ float shs[1024], sws[1024];
    __shared__ float al[16];
    __shared__ float wf[144];
    __shared__ float red[4][16];
    for (int t = tid; t < 1024; t += 256){ shs[t] = sh[bg*1024+t]; sws[t] = sw[bg*1024+t]; }
    if (tid<16) al[tid] = alpha[bg*16+tid];
    if (tid<144) wf[tid] = weff[tid];
    if (tid<160){ int c = tid/10, rr = tid - c*10; ldsx[(c*10+rr)*66] = 0.f; ldsx[(c*10+rr)*66+65] = 0.f; }
    __syncthreads();
    float cstv = cst[bg];
    const float4* x4 = (const float4*)(x + (size_t)bg*65536);
    int j = tid & 63, rl = tid >> 6;
    float psum[16];
    #pragma unroll
    for (int c=0;c<16;++c) psum[c]=0.f;

    for (int s=0;s<8;++s){
        int r0 = s*8;
        #pragma unroll
        for (int it=0; it<10; ++it){
            int f = it*256 + tid;            // 0..2559
            int c = f/160; int rem = f - c*160;
            int row = rem >> 4; int j4 = rem & 15;
            int gr = r0 - 1 + row;
            float4 v;
            if (gr >= 0 && gr < 64) v = x4[c*1024 + gr*16 + j4];
            else { v.x=0.f; v.y=0.f; v.z=0.f; v.w=0.f; }
            float* d = &ldsx[(c*10+row)*66 + 1 + j4*4];
            d[0]=v.x; d[1]=v.y; d[2]=v.z; d[3]=v.w;
        }
        __syncthreads();
        #pragma unroll
        for (int p=0;p<2;++p){
            int ri = rl + p*4;
            int gi = r0 + ri;
            float acc = 0.f, gt = 0.f;
            #pragma unroll
            for (int c=0;c<16;++c){
                const float* lb = &ldsx[c*660 + ri*66 + j];
                float center = lb[67];
                acc += wf[c*9+0]*lb[0]   + wf[c*9+1]*lb[1]   + wf[c*9+2]*lb[2]
                     + wf[c*9+3]*lb[66]  + wf[c*9+4]*center  + wf[c*9+5]*lb[68]
                     + wf[c*9+6]*lb[132] + wf[c*9+7]*lb[133] + wf[c*9+8]*lb[134];
                gt += al[c]*shs[c*64+gi]*sws[c*64+j]*center;
            }
            float sg = sigmoidf_(acc + gt + cstv);
            sigbuf[bg*4096 + gi*64 + j] = sg;
            #pragma unroll
            for (int c=0;c<16;++c){
                psum[c] += ldsx[c*660 + (ri+1)*66 + 1 + j]*sg;
            }
        }
        __syncthreads();
    }
    #pragma unroll
    for (int c=0;c<16;++c){
        float v = psum[c];
        v += __shfl_xor(v,1); v += __shfl_xor(v,2); v += __shfl_xor(v,4);
        v += __shfl_xor(v,8); v += __shfl_xor(v,16); v += __shfl_xor(v,32);
        psum[c]=v;
    }
    int lane = tid & 63, wid = tid >> 6;
    if (lane==0){
        #pragma unroll
        for (int c=0;c<16;++c) red[wid][c]=psum[c];
    }
    __syncthreads();
    if (tid<16){
        float tot = red[0][tid]+red[1][tid]+red[2][tid]+red[3][tid];
        int bgc = bg*16+tid;
        float g0 = gamma[0];
        p2[bgc] = tot*(1.0f/4096.0f) + g0*se1[bgc]*chansum[bgc]*(1.0f/4096.0f);
    }
}

// ---------------- K7: out = x * (sig + gamma*se1) * se2 ----------------
__global__ __launch_bounds__(256) void k7_out(const float* __restrict__ x,
    const float* __restrict__ sigbuf, const float* __restrict__ se1,
    const float* __restrict__ se2, const float* __restrict__ gamma,
    float* __restrict__ out)
{
    const float4* x4 = (const float4*)x;
    const float4* s4 = (const float4*)sigbuf;
    float4* o4 = (float4*)out;
    float g0 = gamma[0];
    int idx = blockIdx.x*256 + threadIdx.x;
    int stride = gridDim.x*256;
    for (int g4 = idx; g4 < 8388608; g4 += stride){
        int e = g4 << 2;
        int bC = e >> 12;
        int pix4 = g4 & 1023;
        int bg = bC >> 4;
        float4 xv = x4[g4];
        float4 sg = s4[bg*1024 + pix4];
        float f1 = g0*se1[bC];
        float s2v = se2[bC];
        float4 ov;
        ov.x = xv.x*(sg.x+f1)*s2v;
        ov.y = xv.y*(sg.y+f1)*s2v;
        ov.z = xv.z*(sg.z+f1)*s2v;
        ov.w = xv.w*(sg.w+f1)*s2v;
        o4[g4] = ov;
    }
}

extern "C" void kernel_launch(void* const* d_in, const int* in_sizes, int n_in,
                              void* d_out, int out_size, void* d_ws, size_t ws_size,
                              hipStream_t stream)
{
    const float* x     = (const float*)d_in[0];
    const float* w1    = (const float*)d_in[1];
    const float* b1    = (const float*)d_in[2];
    const float* w3    = (const float*)d_in[3];
    const float* b3    = (const float*)d_in[4];
    const float* gn_w  = (const float*)d_in[5];
    const float* gn_b  = (const float*)d_in[6];
    const float* cg_w1 = (const float*)d_in[7];
    const float* cg_b1 = (const float*)d_in[8];
    const float* cg_w2 = (const float*)d_in[9];
    const float* cg_b2 = (const float*)d_in[10];
    const float* ga_w1 = (const float*)d_in[11];
    const float* ga_b1 = (const float*)d_in[12];
    const float* ga_w2 = (const float*)d_in[13];
    const float* ga_b2 = (const float*)d_in[14];
    const float* gamma = (const float*)d_in[15];
    float* out = (float*)d_out;
    float* ws  = (float*)d_ws;

    // workspace layout (float offsets)
    float* rs      = ws + 0;         // 512*16*64
    float* cs      = ws + 524288;    // 512*16*64
    float* chansum = ws + 1048576;   // 8192
    float* corners = ws + 1056768;   // 8192*4
    float* sh      = ws + 1089536;   // 512*16*64
    float* sw      = ws + 1613824;   // 512*16*64
    float* se1     = ws + 2138112;   // 8192
    float* mu      = ws + 2146304;   // 8192
    float* rstd    = ws + 2154496;   // 8192
    float* alpha   = ws + 2162688;   // 8192
    float* cst     = ws + 2170880;   // 512
    float* weff    = ws + 2171392;   // 144
    float* bconst  = ws + 2171536;   // 1
    float* sigbuf  = ws + 2171904;   // 512*4096 (16B aligned)
    float* p2      = ws + 4269056;   // 8192
    float* se2     = ws + 4277248;   // 8192
    // total 4285440 floats = ~16.4 MiB

    k1_rowcol<<<8192,256,0,stream>>>(x, rs, cs, chansum, corners);
    k0_weff<<<1,256,0,stream>>>(w3, b3, gn_b, weff, bconst);
    k2_gates<<<512,128,0,stream>>>(rs, cs, w1, b1, sh, sw);
    k_se<<<16,512,0,stream>>>(chansum, 1.0f/4096.0f, cg_w1, cg_b1, cg_w2, cg_b2, se1);
    k3_stats<<<8192,256,0,stream>>>(x, sh, sw, mu, rstd);
    k4_a21<<<512,256,0,stream>>>(w3, b3, gn_w, gn_b, rs, cs, chansum, corners, mu, rstd, bconst, alpha, cst);
    k5_wv<<<512,256,0,stream>>>(x, sh, sw, alpha, cst, weff, se1, chansum, gamma, sigbuf, p2);
    k_se<<<16,512,0,stream>>>(p2, 1.0f, ga_w1, ga_b1, ga_w2, ga_b2, se2);
    k7_out<<<8192,256,0,stream>>>(x, sigbuf, se1, se2, gamma, out);
}

// Round 2
// 205.115 us; speedup vs baseline: 1.4875x; 1.4875x over previous
//
#include <hip/hip_runtime.h>
#include <math.h>

#define EPS 1e-5f

__device__ __forceinline__ float sigmoidf_(float v){ return 1.0f/(1.0f+expf(-v)); }

// ---------------- K1: per-(bg,c) row sums, col sums, total, corners ----------------
__global__ __launch_bounds__(256) void k1_rowcol(const float* __restrict__ x,
    float* __restrict__ rs, float* __restrict__ cs, float* __restrict__ chansum,
    float* __restrict__ corners)
{
    const int bgc = blockIdx.x;           // b*512 + C  == bg*16 + c
    const int tid = threadIdx.x;
    __shared__ float srow[64];
    __shared__ float scol[64];
    if (tid < 64) scol[tid] = 0.0f;
    __syncthreads();
    const float4* x4 = (const float4*)(x + (size_t)bgc * 4096);
    float c0=0.f,c1=0.f,c2=0.f,c3=0.f;
    #pragma unroll
    for (int it=0; it<4; ++it){
        int f = it*256 + tid;
        float4 v = x4[f];
        int i = f >> 4;
        float rsum = v.x+v.y+v.z+v.w;
        rsum += __shfl_xor(rsum, 1);
        rsum += __shfl_xor(rsum, 2);
        rsum += __shfl_xor(rsum, 4);
        rsum += __shfl_xor(rsum, 8);
        if ((tid & 15)==0) srow[i] = rsum;
        c0+=v.x; c1+=v.y; c2+=v.z; c3+=v.w;
    }
    int jb = (tid & 15)*4;
    atomicAdd(&scol[jb+0], c0);
    atomicAdd(&scol[jb+1], c1);
    atomicAdd(&scol[jb+2], c2);
    atomicAdd(&scol[jb+3], c3);
    __syncthreads();
    if (tid < 64){
        float v = srow[tid];
        float t = v;
        t += __shfl_xor(t,1); t += __shfl_xor(t,2); t += __shfl_xor(t,4);
        t += __shfl_xor(t,8); t += __shfl_xor(t,16); t += __shfl_xor(t,32);
        if (tid==0) chansum[bgc] = t;
        rs[bgc*64 + tid] = v;
        cs[bgc*64 + tid] = scol[tid];
    }
    if (tid == 0){
        const float* xb = x + (size_t)bgc*4096;
        corners[bgc*4+0] = xb[0];        // (row0,col0)
        corners[bgc*4+1] = xb[63];       // (row0,col63)
        corners[bgc*4+2] = xb[63*64];    // (row63,col0)
        corners[bgc*4+3] = xb[4095];     // (row63,col63)
    }
}

// ---------------- K0: weff = sum_o a11[o]*w3[o], bconst = sum_o a11[o]*b3[o]; a11 = softmax(gn_b) ----------------
__global__ __launch_bounds__(256) void k0_weff(const float* __restrict__ w3, const float* __restrict__ b3,
    const float* __restrict__ gn_b, float* __restrict__ weff, float* __restrict__ bconst)
{
    __shared__ float a11[16];
    int tid = threadIdx.x;
    if (tid==0){
        float m = gn_b[0];
        for (int i=1;i<16;++i) m = fmaxf(m, gn_b[i]);
        float s=0.f, e[16];
        for (int i=0;i<16;++i){ e[i]=expf(gn_b[i]-m); s+=e[i]; }
        for (int i=0;i<16;++i) a11[i]=e[i]/s;
    }
    __syncthreads();
    if (tid<144){
        float acc=0.f;
        for (int o=0;o<16;++o) acc += a11[o]*w3[o*144+tid];
        weff[tid]=acc;
    }
    if (tid==160){
        float acc=0.f;
        for (int o=0;o<16;++o) acc += a11[o]*b3[o];
        bconst[0]=acc;
    }
}

// ---------------- K2: gates sh/sw: sigmoid(w1 @ [rowmean; colmean] + b1) ----------------
__global__ __launch_bounds__(128) void k2_gates(const float* __restrict__ rs, const float* __restrict__ cs,
    const float* __restrict__ w1, const float* __restrict__ b1,
    float* __restrict__ sh, float* __restrict__ sw)
{
    int bg = blockIdx.x, l = threadIdx.x;
    __shared__ float w1s[256], b1s[16];
    w1s[l] = w1[l]; w1s[l+128] = w1[l+128];
    if (l<16) b1s[l]=b1[l];
    __syncthreads();
    float cat[16];
    bool isrow = l < 64;
    int p = isrow ? l : (l-64);
    const float* src = isrow ? rs : cs;
    #pragma unroll
    for (int c=0;c<16;++c) cat[c] = src[bg*1024 + c*64 + p]*(1.0f/64.0f);
    #pragma unroll
    for (int o=0;o<16;++o){
        float acc = b1s[o];
        #pragma unroll
        for (int c=0;c<16;++c) acc += w1s[o*16+c]*cat[c];
        float sg = sigmoidf_(acc);
        if (isrow) sh[bg*1024 + o*64 + p] = sg;
        else       sw[bg*1024 + o*64 + p] = sg;
    }
}

// ---------------- SE block for se1: 512 -> relu(32) -> sigmoid(512) ----------------
__global__ __launch_bounds__(512) void k_se(const float* __restrict__ pin, float scale,
    const float* __restrict__ wa, const float* __restrict__ ba,
    const float* __restrict__ wb, const float* __restrict__ bb,
    float* __restrict__ seout)
{
    int b = blockIdx.x, tid = threadIdx.x;
    __shared__ float pv[512];
    __shared__ float hdn[32];
    pv[tid] = pin[b*512+tid]*scale;
    __syncthreads();
    if (tid<32){
        float acc = ba[tid];
        const float* wr = wa + tid*512;
        for (int k=0;k<512;++k) acc += wr[k]*pv[k];
        hdn[tid] = fmaxf(acc, 0.0f);
    }
    __syncthreads();
    float acc = bb[tid];
    const float* wr = wb + tid*32;
    #pragma unroll
    for (int k=0;k<32;++k) acc += wr[k]*hdn[k];
    seout[b*512+tid] = sigmoidf_(acc);
}

// ---------------- SE block for se2: builds pin from p2part halves + gamma*se1*chansum ----------------
__global__ __launch_bounds__(512) void k_se2(const float* __restrict__ p2part,
    const float* __restrict__ se1, const float* __restrict__ chansum,
    const float* __restrict__ gamma,
    const float* __restrict__ wa, const float* __restrict__ ba,
    const float* __restrict__ wb, const float* __restrict__ bb,
    float* __restrict__ seout)
{
    int b = blockIdx.x, tid = threadIdx.x;
    __shared__ float pv[512];
    __shared__ float hdn[32];
    int bg = b*32 + (tid>>4);
    int c  = tid & 15;
    float praw = p2part[(bg*2)*16 + c] + p2part[(bg*2+1)*16 + c];
    int bc = b*512 + tid;
    float g0 = gamma[0];
    pv[tid] = (praw + g0*se1[bc]*chansum[bc]) * (1.0f/4096.0f);
    __syncthreads();
    if (tid<32){
        float acc = ba[tid];
        const float* wr = wa + tid*512;
        for (int k=0;k<512;++k) acc += wr[k]*pv[k];
        hdn[tid] = fmaxf(acc, 0.0f);
    }
    __syncthreads();
    float acc = bb[tid];
    const float* wr = wb + tid*32;
    #pragma unroll
    for (int k=0;k<32;++k) acc += wr[k]*hdn[k];
    seout[b*512+tid] = sigmoidf_(acc);
}

// ---------------- K3: instance-norm stats of x1 = gx*sh_i*sw_j ----------------
__global__ __launch_bounds__(256) void k3_stats(const float* __restrict__ x,
    const float* __restrict__ sh, const float* __restrict__ sw,
    float* __restrict__ mu, float* __restrict__ rstd)
{
    int bgc = blockIdx.x, tid = threadIdx.x;
    int bg = bgc >> 4, c = bgc & 15;
    __shared__ float shv[64], swv[64];
    __shared__ float r1[4], r2[4];
    if (tid<64) shv[tid] = sh[bg*1024 + c*64 + tid];
    else if (tid<128) swv[tid-64] = sw[bg*1024 + c*64 + (tid-64)];
    __syncthreads();
    const float4* x4 = (const float4*)(x + (size_t)bgc*4096);
    float s1=0.f, s2=0.f;
    int jb = (tid&15)*4;
    #pragma unroll
    for (int it=0; it<4; ++it){
        int f = it*256+tid;
        float4 v = x4[f];
        int i = f>>4;
        float si = shv[i];
        float a0 = v.x*si*swv[jb+0];
        float a1 = v.y*si*swv[jb+1];
        float a2 = v.z*si*swv[jb+2];
        float a3 = v.w*si*swv[jb+3];
        s1 += a0+a1+a2+a3;
        s2 += a0*a0+a1*a1+a2*a2+a3*a3;
    }
    #pragma unroll
    for (int m=1; m<64; m<<=1){ s1 += __shfl_xor(s1,m); s2 += __shfl_xor(s2,m); }
    int lane = tid&63, wid = tid>>6;
    if (lane==0){ r1[wid]=s1; r2[wid]=s2; }
    __syncthreads();
    if (tid==0){
        float S1 = r1[0]+r1[1]+r1[2]+r1[3];
        float S2 = r2[0]+r2[1]+r2[2]+r2[3];
        float m = S1*(1.0f/4096.0f);
        float var = S2*(1.0f/4096.0f) - m*m;
        mu[bgc]=m;
        rstd[bgc]=rsqrtf(var+EPS);
    }
}

// ---------------- K4: analytic mean(x2) -> a21 -> alpha, cst ----------------
__global__ __launch_bounds__(256) void k4_a21(const float* __restrict__ w3, const float* __restrict__ b3,
    const float* __restrict__ gn_w, const float* __restrict__ gn_b,
    const float* __restrict__ rs, const float* __restrict__ cs,
    const float* __restrict__ chansum, const float* __restrict__ corners,
    const float* __restrict__ mu, const float* __restrict__ rstd,
    const float* __restrict__ bconst,
    float* __restrict__ alpha, float* __restrict__ cst)
{
    int bg = blockIdx.x, tid = threadIdx.x;
    __shared__ float w3s[2304];
    __shared__ float regs[144];
    __shared__ float m2[16];
    __shared__ float a21[16];
    #pragma unroll
    for (int k=0;k<9;++k) w3s[tid + k*256] = w3[tid + k*256];
    if (tid < 144){
        int c = tid/9, k = tid - c*9, ky = k/3, kx = k - ky*3;
        int bgc = bg*16 + c;
        float r = chansum[bgc];
        if (ky==0) r -= rs[bgc*64+63];   // shift u=-1 excludes row 63
        if (ky==2) r -= rs[bgc*64+0];    // shift u=+1 excludes row 0
        if (kx==0) r -= cs[bgc*64+63];
        if (kx==2) r -= cs[bgc*64+0];
        if (ky!=1 && kx!=1) r += corners[bgc*4 + ((ky==0)?2:0) + ((kx==0)?1:0)];
        regs[tid] = r;
    }
    __syncthreads();
    if (tid<16){
        float s=0.f;
        const float* wo = w3s + tid*144;
        for (int q=0;q<144;++q) s += wo[q]*regs[q];
        m2[tid] = b3[tid] + s*(1.0f/4096.0f);
    }
    __syncthreads();
    if (tid==0){
        float m = m2[0];
        for (int i=1;i<16;++i) m = fmaxf(m, m2[i]);
        float s=0.f, e[16];
        for (int i=0;i<16;++i){ e[i]=expf(m2[i]-m); s+=e[i]; }
        for (int i=0;i<16;++i) a21[i] = e[i]/s;
    }
    __syncthreads();
    if (tid<16){
        int bgc = bg*16+tid;
        alpha[bgc] = a21[tid]*gn_w[tid]*rstd[bgc];
    }
    if (tid==0){
        float cv = bconst[0];
        for (int c2=0;c2<16;++c2){
            int bgc = bg*16+c2;
            cv += a21[c2]*(gn_b[c2] - gn_w[c2]*rstd[bgc]*mu[bgc]);
        }
        cst[bg] = cv;
    }
}

// ---------------- K5: register-streaming conv + gating; sig=sigmoid(wv); psum partials ----------------
// block = (bg, half); wave w handles 8-row stripe r0 = (half*4+w)*8.
// Horizontal-tap decomposition: A0/A1/A2 column accumulators, combine via shfl.
__global__ __launch_bounds__(256) void k5_wv(const float* __restrict__ x,
    const float* __restrict__ sh, const float* __restrict__ sw,
    const float* __restrict__ alpha, const float* __restrict__ cst,
    const float* __restrict__ weff,
    float* __restrict__ sigbuf, float* __restrict__ p2part)
{
    const int bid = blockIdx.x;
    const int bg  = bid >> 1;
    const int half = bid & 1;
    const int tid = threadIdx.x;
    const int j   = tid & 63;
    const int w   = tid >> 6;         // wave 0..3
    __shared__ float red[4][16];

    const int r0 = __builtin_amdgcn_readfirstlane((half*4 + w) * 8);
    const float* xb  = x + (size_t)bg*65536;    // [16][64][64]
    const float* shb = sh + bg*1024;
    const float* swb = sw + bg*1024;
    const float* alb = alpha + bg*16;
    const float cstv = cst[bg];

    float A0[8], A1[8], A2[8], G[8];
    #pragma unroll
    for (int r=0;r<8;++r){ A0[r]=0.f; A1[r]=0.f; A2[r]=0.f; G[r]=0.f; }

    #pragma unroll 1
    for (int c=0;c<16;++c){
        const float* xc = xb + c*4096;
        const float* wq = weff + c*9;          // uniform -> s_loads
        float w0=wq[0], w1_=wq[1], w2=wq[2];
        float w3_=wq[3], w4=wq[4], w5=wq[5];
        float w6=wq[6], w7=wq[7], w8=wq[8];
        float alc = alb[c];
        float swv = swb[c*64 + j];
        float v[10];
        #pragma unroll
        for (int k=0;k<10;++k){
            int t = r0 - 1 + k;
            int tc = t < 0 ? 0 : (t > 63 ? 63 : t);
            float val = xc[tc*64 + j];
            v[k] = (t >= 0 && t < 64) ? val : 0.f;
        }
        #pragma unroll
        for (int k=0;k<10;++k){
            if (k<=7){ A0[k]+=w0*v[k]; A1[k]+=w1_*v[k]; A2[k]+=w2*v[k]; }
            if (k>=1 && k<=8){
                A0[k-1]+=w3_*v[k]; A1[k-1]+=w4*v[k]; A2[k-1]+=w5*v[k];
                float u = alc * shb[c*64 + (r0+k-1)];   // uniform (s_load + s_mul)
                G[k-1] += u * (swv * v[k]);
            }
            if (k>=2){ A0[k-2]+=w6*v[k]; A1[k-2]+=w7*v[k]; A2[k-2]+=w8*v[k]; }
        }
    }

    float sg[8];
    #pragma unroll
    for (int r=0;r<8;++r){
        float l = __shfl_up(A0[r], 1);
        if (j==0) l = 0.f;
        float rr = __shfl_down(A2[r], 1);
        if (j==63) rr = 0.f;
        float s = sigmoidf_(l + A1[r] + rr + G[r] + cstv);
        sg[r] = s;
        sigbuf[bg*4096 + (r0+r)*64 + j] = s;
    }

    // psum partials: sum_r x[c][r0+r][j]*sg[r], reduce over lanes, then waves
    #pragma unroll 1
    for (int c=0;c<16;++c){
        const float* xc = xb + c*4096;
        float acc = 0.f;
        #pragma unroll
        for (int r=0;r<8;++r) acc += xc[(r0+r)*64 + j]*sg[r];
        #pragma unroll
        for (int m=1;m<64;m<<=1) acc += __shfl_xor(acc, m);
        if (j==0) red[w][c] = acc;
    }
    __syncthreads();
    if (tid<16){
        p2part[bid*16 + tid] = red[0][tid]+red[1][tid]+red[2][tid]+red[3][tid];
    }
}

// ---------------- K7: out = x * (sig + gamma*se1) * se2 ----------------
__global__ __launch_bounds__(256) void k7_out(const float* __restrict__ x,
    const float* __restrict__ sigbuf, const float* __restrict__ se1,
    const float* __restrict__ se2, const float* __restrict__ gamma,
    float* __restrict__ out)
{
    const float4* x4 = (const float4*)x;
    const float4* s4 = (const float4*)sigbuf;
    float4* o4 = (float4*)out;
    float g0 = gamma[0];
    int idx = blockIdx.x*256 + threadIdx.x;
    int stride = gridDim.x*256;
    for (int g4 = idx; g4 < 8388608; g4 += stride){
        int e = g4 << 2;
        int bC = e >> 12;
        int pix4 = g4 & 1023;
        int bg = bC >> 4;
        float4 xv = x4[g4];
        float4 sg = s4[bg*1024 + pix4];
        float f1 = g0*se1[bC];
        float s2v = se2[bC];
        float4 ov;
        ov.x = xv.x*(sg.x+f1)*s2v;
        ov.y = xv.y*(sg.y+f1)*s2v;
        ov.z = xv.z*(sg.z+f1)*s2v;
        ov.w = xv.w*(sg.w+f1)*s2v;
        o4[g4] = ov;
    }
}

extern "C" void kernel_launch(void* const* d_in, const int* in_sizes, int n_in,
                              void* d_out, int out_size, void* d_ws, size_t ws_size,
                              hipStream_t stream)
{
    const float* x     = (const float*)d_in[0];
    const float* w1    = (const float*)d_in[1];
    const float* b1    = (const float*)d_in[2];
    const float* w3    = (const float*)d_in[3];
    const float* b3    = (const float*)d_in[4];
    const float* gn_w  = (const float*)d_in[5];
    const float* gn_b  = (const float*)d_in[6];
    const float* cg_w1 = (const float*)d_in[7];
    const float* cg_b1 = (const float*)d_in[8];
    const float* cg_w2 = (const float*)d_in[9];
    const float* cg_b2 = (const float*)d_in[10];
    const float* ga_w1 = (const float*)d_in[11];
    const float* ga_b1 = (const float*)d_in[12];
    const float* ga_w2 = (const float*)d_in[13];
    const float* ga_b2 = (const float*)d_in[14];
    const float* gamma = (const float*)d_in[15];
    float* out = (float*)d_out;
    float* ws  = (float*)d_ws;

    // workspace layout (float offsets)
    float* rs      = ws + 0;         // 512*16*64   (dead after k4 -> reused as p2part)
    float* cs      = ws + 524288;    // 512*16*64
    float* chansum = ws + 1048576;   // 8192
    float* corners = ws + 1056768;   // 8192*4
    float* sh      = ws + 1089536;   // 512*16*64
    float* sw      = ws + 1613824;   // 512*16*64
    float* se1     = ws + 2138112;   // 8192
    float* mu      = ws + 2146304;   // 8192
    float* rstd    = ws + 2154496;   // 8192
    float* alpha   = ws + 2162688;   // 8192
    float* cst     = ws + 2170880;   // 512
    float* weff    = ws + 2171392;   // 144
    float* bconst  = ws + 2171536;   // 1
    float* sigbuf  = ws + 2171904;   // 512*4096 (16B aligned)
    float* se2     = ws + 4277248;   // 8192
    float* p2part  = rs;             // 1024*16, aliases rs (dead after k4)

    k1_rowcol<<<8192,256,0,stream>>>(x, rs, cs, chansum, corners);
    k0_weff<<<1,256,0,stream>>>(w3, b3, gn_b, weff, bconst);
    k2_gates<<<512,128,0,stream>>>(rs, cs, w1, b1, sh, sw);
    k_se<<<16,512,0,stream>>>(chansum, 1.0f/4096.0f, cg_w1, cg_b1, cg_w2, cg_b2, se1);
    k3_stats<<<8192,256,0,stream>>>(x, sh, sw, mu, rstd);
    k4_a21<<<512,256,0,stream>>>(w3, b3, gn_w, gn_b, rs, cs, chansum, corners, mu, rstd, bconst, alpha, cst);
    k5_wv<<<1024,256,0,stream>>>(x, sh, sw, alpha, cst, weff, sigbuf, p2part);
    k_se2<<<16,512,0,stream>>>(p2part, se1, chansum, gamma, ga_w1, ga_b1, ga_w2, ga_b2, se2);
    k7_out<<<8192,256,0,stream>>>(x, sigbuf, se1, se2, gamma, out);
}

// Round 4
// 166.985 us; speedup vs baseline: 1.8271x; 1.2283x over previous
//
#include <hip/hip_runtime.h>
#include <math.h>

#define EPS 1e-5f

typedef float __attribute__((ext_vector_type(4))) floatx4;

__device__ __forceinline__ float sigmoidf_(float v){ return 1.0f/(1.0f+expf(-v)); }

// ---------------- K0: weff = sum_o a11[o]*w3[o], bconst = sum_o a11[o]*b3[o]; a11 = softmax(gn_b) ----------------
__global__ __launch_bounds__(256) void k0_weff(const float* __restrict__ w3, const float* __restrict__ b3,
    const float* __restrict__ gn_b, float* __restrict__ weff, float* __restrict__ bconst)
{
    __shared__ float a11[16];
    int tid = threadIdx.x;
    if (tid==0){
        float m = gn_b[0];
        for (int i=1;i<16;++i) m = fmaxf(m, gn_b[i]);
        float s=0.f, e[16];
        for (int i=0;i<16;++i){ e[i]=expf(gn_b[i]-m); s+=e[i]; }
        for (int i=0;i<16;++i) a11[i]=e[i]/s;
    }
    __syncthreads();
    if (tid<144){
        float acc=0.f;
        for (int o=0;o<16;++o) acc += a11[o]*w3[o*144+tid];
        weff[tid]=acc;
    }
    if (tid==160){
        float acc=0.f;
        for (int o=0;o<16;++o) acc += a11[o]*b3[o];
        bconst[0]=acc;
    }
}

// ---------------- KA: fused k1(sums)+k2(gates)+k3(stats)+k4(a21/alpha/cst), one block per bg ----------------
__global__ __launch_bounds__(1024) void kA(const float* __restrict__ x,
    const float* __restrict__ w1, const float* __restrict__ b1,
    const float* __restrict__ w3, const float* __restrict__ b3,
    const float* __restrict__ gn_w, const float* __restrict__ gn_b,
    float* __restrict__ sh, float* __restrict__ sw,
    float* __restrict__ chansum, float* __restrict__ alpha, float* __restrict__ cst)
{
    const int bg = blockIdx.x;
    const int tid = threadIdx.x;
    const int w = tid >> 6;        // wave = channel 0..15
    const int lane = tid & 63;

    __shared__ float rs_s[16][64], cs_s[16][64];
    __shared__ float sh_s[16][64], sw_s[16][64];
    __shared__ float chs_s[16], corn_s[16][4], mu_s[16], rstd_s[16];
    __shared__ float w3s[2304], w1s[256], b1s[16];
    __shared__ float regs[144], m2[16], a21_s[16];

    for (int t=tid; t<2304; t+=1024) w3s[t] = w3[t];
    if (tid < 256) w1s[tid] = w1[tid];
    if (tid < 16)  b1s[tid] = b1[tid];

    const float4* xc4 = (const float4*)(x + (((size_t)bg<<4) + w)*4096);

    // ---- phase 1: row sums / col sums / total / corners (per-wave, own channel) ----
    float c0=0.f,c1=0.f,c2=0.f,c3=0.f;
    #pragma unroll
    for (int it=0; it<16; ++it){
        float4 v = xc4[it*64 + lane];
        float rsum = v.x+v.y+v.z+v.w;
        rsum += __shfl_xor(rsum,1); rsum += __shfl_xor(rsum,2);
        rsum += __shfl_xor(rsum,4); rsum += __shfl_xor(rsum,8);
        if ((lane&15)==0) rs_s[w][it*4 + (lane>>4)] = rsum;
        c0+=v.x; c1+=v.y; c2+=v.z; c3+=v.w;
    }
    c0 += __shfl_xor(c0,16); c0 += __shfl_xor(c0,32);
    c1 += __shfl_xor(c1,16); c1 += __shfl_xor(c1,32);
    c2 += __shfl_xor(c2,16); c2 += __shfl_xor(c2,32);
    c3 += __shfl_xor(c3,16); c3 += __shfl_xor(c3,32);
    float tsum = c0+c1+c2+c3;
    tsum += __shfl_xor(tsum,1); tsum += __shfl_xor(tsum,2);
    tsum += __shfl_xor(tsum,4); tsum += __shfl_xor(tsum,8);
    if (lane < 16){
        cs_s[w][lane*4+0]=c0; cs_s[w][lane*4+1]=c1;
        cs_s[w][lane*4+2]=c2; cs_s[w][lane*4+3]=c3;
    }
    if (lane==0){
        chs_s[w]=tsum;
        chansum[(bg<<4)+w]=tsum;
        const float* xb = x + (((size_t)bg<<4)+w)*4096;
        corn_s[w][0]=xb[0]; corn_s[w][1]=xb[63];
        corn_s[w][2]=xb[4032]; corn_s[w][3]=xb[4095];
    }
    __syncthreads();

    // ---- phase 2: gates sh/sw (2048 dots of length 16; each thread does 2) ----
    {
        int p  = tid & 127;
        int o0 = tid >> 7;           // 0..7
        bool isrow = (p < 64);       // wave-uniform
        int pp = p & 63;
        float cat[16];
        #pragma unroll
        for (int cc=0; cc<16; ++cc)
            cat[cc] = (isrow ? rs_s[cc][pp] : cs_s[cc][pp]) * (1.0f/64.0f);
        #pragma unroll
        for (int t2=0; t2<2; ++t2){
            int o = o0 + t2*8;
            float acc = b1s[o];
            #pragma unroll
            for (int cc=0; cc<16; ++cc) acc += w1s[o*16+cc]*cat[cc];
            float sg = sigmoidf_(acc);
            if (isrow){ sh_s[o][pp]=sg; sh[bg*1024 + o*64 + pp]=sg; }
            else      { sw_s[o][pp]=sg; sw[bg*1024 + o*64 + pp]=sg; }
        }
    }
    __syncthreads();

    // ---- phase 3: instance-norm stats of x1 = x*sh_i*sw_j (x re-read is L2/L3-hot) ----
    {
        int jb = (lane&15)*4;
        float sw0=sw_s[w][jb], sw1=sw_s[w][jb+1], sw2=sw_s[w][jb+2], sw3=sw_s[w][jb+3];
        float s1=0.f, s2=0.f;
        #pragma unroll
        for (int it=0; it<16; ++it){
            float4 v = xc4[it*64+lane];
            float si = sh_s[w][it*4+(lane>>4)];
            float a0=v.x*si*sw0, a1=v.y*si*sw1, a2=v.z*si*sw2, a3=v.w*si*sw3;
            s1 += a0+a1+a2+a3;
            s2 += a0*a0+a1*a1+a2*a2+a3*a3;
        }
        #pragma unroll
        for (int m=1;m<64;m<<=1){ s1+=__shfl_xor(s1,m); s2+=__shfl_xor(s2,m); }
        if (lane==0){
            float mu = s1*(1.0f/4096.0f);
            float var = s2*(1.0f/4096.0f) - mu*mu;
            mu_s[w]=mu; rstd_s[w]=rsqrtf(var+EPS);
        }
    }
    __syncthreads();

    // ---- phase 4: analytic mean(x2) -> a21 -> alpha, cst (all from LDS) ----
    if (tid < 144){
        int c = tid/9, k = tid - c*9, ky = k/3, kx = k - ky*3;
        float r = chs_s[c];
        if (ky==0) r -= rs_s[c][63];
        if (ky==2) r -= rs_s[c][0];
        if (kx==0) r -= cs_s[c][63];
        if (kx==2) r -= cs_s[c][0];
        if (ky!=1 && kx!=1) r += corn_s[c][((ky==0)?2:0)+((kx==0)?1:0)];
        regs[tid] = r;
    }
    __syncthreads();
    if (tid<16){
        float s=0.f;
        const float* wo = w3s + tid*144;
        for (int q=0;q<144;++q) s += wo[q]*regs[q];
        m2[tid] = b3[tid] + s*(1.0f/4096.0f);
    }
    __syncthreads();
    if (tid==0){
        float m = m2[0];
        for (int i=1;i<16;++i) m = fmaxf(m, m2[i]);
        float s=0.f, e[16];
        for (int i=0;i<16;++i){ e[i]=expf(m2[i]-m); s+=e[i]; }
        for (int i=0;i<16;++i) a21_s[i]=e[i]/s;
    }
    __syncthreads();
    if (tid<16){
        alpha[(bg<<4)+tid] = a21_s[tid]*gn_w[tid]*rstd_s[tid];
    }
    if (tid==0){
        float cv=0.f;
        for (int c2=0;c2<16;++c2)
            cv += a21_s[c2]*(gn_b[c2] - gn_w[c2]*rstd_s[c2]*mu_s[c2]);
        cst[bg]=cv;
    }
}

// ---------------- SE block for se1: 512 -> relu(32) -> sigmoid(512) ----------------
__global__ __launch_bounds__(512) void k_se(const float* __restrict__ pin, float scale,
    const float* __restrict__ wa, const float* __restrict__ ba,
    const float* __restrict__ wb, const float* __restrict__ bb,
    float* __restrict__ seout)
{
    int b = blockIdx.x, tid = threadIdx.x;
    __shared__ float pv[512];
    __shared__ float hdn[32];
    pv[tid] = pin[b*512+tid]*scale;
    __syncthreads();
    if (tid<32){
        float acc = ba[tid];
        const float* wr = wa + tid*512;
        for (int k=0;k<512;++k) acc += wr[k]*pv[k];
        hdn[tid] = fmaxf(acc, 0.0f);
    }
    __syncthreads();
    float acc = bb[tid];
    const float* wr = wb + tid*32;
    #pragma unroll
    for (int k=0;k<32;++k) acc += wr[k]*hdn[k];
    seout[b*512+tid] = sigmoidf_(acc);
}

// ---------------- SE block for se2: builds pin from p2part halves + gamma*se1*chansum ----------------
__global__ __launch_bounds__(512) void k_se2(const float* __restrict__ p2part,
    const float* __restrict__ se1, const float* __restrict__ chansum,
    const float* __restrict__ gamma,
    const float* __restrict__ wa, const float* __restrict__ ba,
    const float* __restrict__ wb, const float* __restrict__ bb,
    float* __restrict__ seout)
{
    int b = blockIdx.x, tid = threadIdx.x;
    __shared__ float pv[512];
    __shared__ float hdn[32];
    int bg = b*32 + (tid>>4);
    int c  = tid & 15;
    float praw = p2part[(bg*2)*16 + c] + p2part[(bg*2+1)*16 + c];
    int bc = b*512 + tid;
    float g0 = gamma[0];
    pv[tid] = (praw + g0*se1[bc]*chansum[bc]) * (1.0f/4096.0f);
    __syncthreads();
    if (tid<32){
        float acc = ba[tid];
        const float* wr = wa + tid*512;
        for (int k=0;k<512;++k) acc += wr[k]*pv[k];
        hdn[tid] = fmaxf(acc, 0.0f);
    }
    __syncthreads();
    float acc = bb[tid];
    const float* wr = wb + tid*32;
    #pragma unroll
    for (int k=0;k<32;++k) acc += wr[k]*hdn[k];
    seout[b*512+tid] = sigmoidf_(acc);
}

// ---------------- K5: register-streaming conv + gating; sig=sigmoid(wv); psum partials ----------------
__global__ __launch_bounds__(256) void k5_wv(const float* __restrict__ x,
    const float* __restrict__ sh, const float* __restrict__ sw,
    const float* __restrict__ alpha, const float* __restrict__ cst,
    const float* __restrict__ weff, const float* __restrict__ bconst,
    float* __restrict__ sigbuf, float* __restrict__ p2part)
{
    const int bid = blockIdx.x;
    const int bg  = bid >> 1;
    const int half = bid & 1;
    const int tid = threadIdx.x;
    const int j   = tid & 63;
    const int w   = tid >> 6;         // wave 0..3
    __shared__ float red[4][16];

    const int r0 = __builtin_amdgcn_readfirstlane((half*4 + w) * 8);
    const float* xb  = x + (size_t)bg*65536;    // [16][64][64]
    const float* shb = sh + bg*1024;
    const float* swb = sw + bg*1024;
    const float* alb = alpha + bg*16;
    const float cstv = cst[bg] + bconst[0];

    float A0[8], A1[8], A2[8], G[8];
    #pragma unroll
    for (int r=0;r<8;++r){ A0[r]=0.f; A1[r]=0.f; A2[r]=0.f; G[r]=0.f; }

    #pragma unroll 1
    for (int c=0;c<16;++c){
        const float* xc = xb + c*4096;
        const float* wq = weff + c*9;          // uniform -> s_loads
        float w0=wq[0], w1_=wq[1], w2=wq[2];
        float w3_=wq[3], w4=wq[4], w5=wq[5];
        float w6=wq[6], w7=wq[7], w8=wq[8];
        float alc = alb[c];
        float swv = swb[c*64 + j];
        float v[10];
        #pragma unroll
        for (int k=0;k<10;++k){
            int t = r0 - 1 + k;
            int tc = t < 0 ? 0 : (t > 63 ? 63 : t);
            float val = xc[tc*64 + j];
            v[k] = (t >= 0 && t < 64) ? val : 0.f;
        }
        #pragma unroll
        for (int k=0;k<10;++k){
            if (k<=7){ A0[k]+=w0*v[k]; A1[k]+=w1_*v[k]; A2[k]+=w2*v[k]; }
            if (k>=1 && k<=8){
                A0[k-1]+=w3_*v[k]; A1[k-1]+=w4*v[k]; A2[k-1]+=w5*v[k];
                float u = alc * shb[c*64 + (r0+k-1)];   // uniform
                G[k-1] += u * (swv * v[k]);
            }
            if (k>=2){ A0[k-2]+=w6*v[k]; A1[k-2]+=w7*v[k]; A2[k-2]+=w8*v[k]; }
        }
    }

    float sg[8];
    #pragma unroll
    for (int r=0;r<8;++r){
        float l = __shfl_up(A0[r], 1);
        if (j==0) l = 0.f;
        float rr = __shfl_down(A2[r], 1);
        if (j==63) rr = 0.f;
        float s = sigmoidf_(l + A1[r] + rr + G[r] + cstv);
        sg[r] = s;
        sigbuf[bg*4096 + (r0+r)*64 + j] = s;
    }

    #pragma unroll 1
    for (int c=0;c<16;++c){
        const float* xc = xb + c*4096;
        float acc = 0.f;
        #pragma unroll
        for (int r=0;r<8;++r) acc += xc[(r0+r)*64 + j]*sg[r];
        #pragma unroll
        for (int m=1;m<64;m<<=1) acc += __shfl_xor(acc, m);
        if (j==0) red[w][c] = acc;
    }
    __syncthreads();
    if (tid<16){
        p2part[bid*16 + tid] = red[0][tid]+red[1][tid]+red[2][tid]+red[3][tid];
    }
}

// ---------------- K7: out = x * (sig + gamma*se1) * se2 ----------------
__global__ __launch_bounds__(256) void k7_out(const float* __restrict__ x,
    const float* __restrict__ sigbuf, const float* __restrict__ se1,
    const float* __restrict__ se2, const float* __restrict__ gamma,
    float* __restrict__ out)
{
    const floatx4* x4 = (const floatx4*)x;
    const floatx4* s4 = (const floatx4*)sigbuf;
    floatx4* o4 = (floatx4*)out;
    float g0 = gamma[0];
    int idx = blockIdx.x*256 + threadIdx.x;
    int stride = gridDim.x*256;
    for (int g4 = idx; g4 < 8388608; g4 += stride){
        int e = g4 << 2;
        int bC = e >> 12;
        int pix4 = g4 & 1023;
        int bg = bC >> 4;
        floatx4 xv = x4[g4];
        floatx4 sg = s4[bg*1024 + pix4];
        float f1 = g0*se1[bC];
        float s2v = se2[bC];
        floatx4 ov;
        ov.x = xv.x*(sg.x+f1)*s2v;
        ov.y = xv.y*(sg.y+f1)*s2v;
        ov.z = xv.z*(sg.z+f1)*s2v;
        ov.w = xv.w*(sg.w+f1)*s2v;
        __builtin_nontemporal_store(ov, &o4[g4]);
    }
}

extern "C" void kernel_launch(void* const* d_in, const int* in_sizes, int n_in,
                              void* d_out, int out_size, void* d_ws, size_t ws_size,
                              hipStream_t stream)
{
    const float* x     = (const float*)d_in[0];
    const float* w1    = (const float*)d_in[1];
    const float* b1    = (const float*)d_in[2];
    const float* w3    = (const float*)d_in[3];
    const float* b3    = (const float*)d_in[4];
    const float* gn_w  = (const float*)d_in[5];
    const float* gn_b  = (const float*)d_in[6];
    const float* cg_w1 = (const float*)d_in[7];
    const float* cg_b1 = (const float*)d_in[8];
    const float* cg_w2 = (const float*)d_in[9];
    const float* cg_b2 = (const float*)d_in[10];
    const float* ga_w1 = (const float*)d_in[11];
    const float* ga_b1 = (const float*)d_in[12];
    const float* ga_w2 = (const float*)d_in[13];
    const float* ga_b2 = (const float*)d_in[14];
    const float* gamma = (const float*)d_in[15];
    float* out = (float*)d_out;
    float* ws  = (float*)d_ws;

    // workspace layout (float offsets)
    float* sh      = ws + 0;         // 524288
    float* sw      = ws + 524288;    // 524288
    float* chansum = ws + 1048576;   // 8192
    float* alpha   = ws + 1056768;   // 8192
    float* cst     = ws + 1064960;   // 512
    float* weff    = ws + 1065472;   // 144
    float* bconst  = ws + 1065616;   // 1
    float* sigbuf  = ws + 1065728;   // 2097152 (16B aligned)
    float* p2part  = ws + 3162880;   // 16384
    float* se1     = ws + 3179264;   // 8192
    float* se2     = ws + 3187456;   // 8192

    k0_weff<<<1,256,0,stream>>>(w3, b3, gn_b, weff, bconst);
    kA<<<512,1024,0,stream>>>(x, w1, b1, w3, b3, gn_w, gn_b, sh, sw, chansum, alpha, cst);
    k_se<<<16,512,0,stream>>>(chansum, 1.0f/4096.0f, cg_w1, cg_b1, cg_w2, cg_b2, se1);
    k5_wv<<<1024,256,0,stream>>>(x, sh, sw, alpha, cst, weff, bconst, sigbuf, p2part);
    k_se2<<<16,512,0,stream>>>(p2part, se1, chansum, gamma, ga_w1, ga_b1, ga_w2, ga_b2, se2);
    k7_out<<<8192,256,0,stream>>>(x, sigbuf, se1, se2, gamma, out);
}

// Round 5
// 164.079 us; speedup vs baseline: 1.8595x; 1.0177x over previous
//
#include <hip/hip_runtime.h>
#include <math.h>

#define EPS 1e-5f

typedef float __attribute__((ext_vector_type(4))) floatx4;

__device__ __forceinline__ float sigmoidf_(float v){ return 1.0f/(1.0f+expf(-v)); }

// ---------------- K0: weff = sum_o a11[o]*w3[o], bconst = sum_o a11[o]*b3[o]; a11 = softmax(gn_b) ----------------
__global__ __launch_bounds__(256) void k0_weff(const float* __restrict__ w3, const float* __restrict__ b3,
    const float* __restrict__ gn_b, float* __restrict__ weff, float* __restrict__ bconst)
{
    __shared__ float a11[16];
    int tid = threadIdx.x;
    if (tid==0){
        float m = gn_b[0];
        for (int i=1;i<16;++i) m = fmaxf(m, gn_b[i]);
        float s=0.f, e[16];
        for (int i=0;i<16;++i){ e[i]=expf(gn_b[i]-m); s+=e[i]; }
        for (int i=0;i<16;++i) a11[i]=e[i]/s;
    }
    __syncthreads();
    if (tid<144){
        float acc=0.f;
        for (int o=0;o<16;++o) acc += a11[o]*w3[o*144+tid];
        weff[tid]=acc;
    }
    if (tid==160){
        float acc=0.f;
        for (int o=0;o<16;++o) acc += a11[o]*b3[o];
        bconst[0]=acc;
    }
}

// ---------------- KA: fused k1(sums)+k2(gates)+k3(stats)+k4(a21/alpha/cst), one block per bg ----------------
__global__ __launch_bounds__(1024) void kA(const float* __restrict__ x,
    const float* __restrict__ w1, const float* __restrict__ b1,
    const float* __restrict__ w3, const float* __restrict__ b3,
    const float* __restrict__ gn_w, const float* __restrict__ gn_b,
    float* __restrict__ sh, float* __restrict__ sw,
    float* __restrict__ chansum, float* __restrict__ alpha, float* __restrict__ cst)
{
    const int bg = blockIdx.x;
    const int tid = threadIdx.x;
    const int w = tid >> 6;        // wave = channel 0..15
    const int lane = tid & 63;

    __shared__ float rs_s[16][64], cs_s[16][64];
    __shared__ float sh_s[16][64], sw_s[16][64];
    __shared__ float chs_s[16], corn_s[16][4], mu_s[16], rstd_s[16];
    __shared__ float w3s[2304], w1s[256], b1s[16];
    __shared__ float regs[144], m2[16], a21_s[16];

    for (int t=tid; t<2304; t+=1024) w3s[t] = w3[t];
    if (tid < 256) w1s[tid] = w1[tid];
    if (tid < 16)  b1s[tid] = b1[tid];

    const float4* xc4 = (const float4*)(x + (((size_t)bg<<4) + w)*4096);

    // ---- phase 1: row sums / col sums / total / corners (per-wave, own channel) ----
    float c0=0.f,c1=0.f,c2=0.f,c3=0.f;
    #pragma unroll
    for (int it=0; it<16; ++it){
        float4 v = xc4[it*64 + lane];
        float rsum = v.x+v.y+v.z+v.w;
        rsum += __shfl_xor(rsum,1); rsum += __shfl_xor(rsum,2);
        rsum += __shfl_xor(rsum,4); rsum += __shfl_xor(rsum,8);
        if ((lane&15)==0) rs_s[w][it*4 + (lane>>4)] = rsum;
        c0+=v.x; c1+=v.y; c2+=v.z; c3+=v.w;
    }
    c0 += __shfl_xor(c0,16); c0 += __shfl_xor(c0,32);
    c1 += __shfl_xor(c1,16); c1 += __shfl_xor(c1,32);
    c2 += __shfl_xor(c2,16); c2 += __shfl_xor(c2,32);
    c3 += __shfl_xor(c3,16); c3 += __shfl_xor(c3,32);
    float tsum = c0+c1+c2+c3;
    tsum += __shfl_xor(tsum,1); tsum += __shfl_xor(tsum,2);
    tsum += __shfl_xor(tsum,4); tsum += __shfl_xor(tsum,8);
    if (lane < 16){
        cs_s[w][lane*4+0]=c0; cs_s[w][lane*4+1]=c1;
        cs_s[w][lane*4+2]=c2; cs_s[w][lane*4+3]=c3;
    }
    if (lane==0){
        chs_s[w]=tsum;
        chansum[(bg<<4)+w]=tsum;
        const float* xb = x + (((size_t)bg<<4)+w)*4096;
        corn_s[w][0]=xb[0]; corn_s[w][1]=xb[63];
        corn_s[w][2]=xb[4032]; corn_s[w][3]=xb[4095];
    }
    __syncthreads();

    // ---- phase 2: gates sh/sw (2048 dots of length 16; each thread does 2) ----
    {
        int p  = tid & 127;
        int o0 = tid >> 7;           // 0..7
        bool isrow = (p < 64);       // wave-uniform
        int pp = p & 63;
        float cat[16];
        #pragma unroll
        for (int cc=0; cc<16; ++cc)
            cat[cc] = (isrow ? rs_s[cc][pp] : cs_s[cc][pp]) * (1.0f/64.0f);
        #pragma unroll
        for (int t2=0; t2<2; ++t2){
            int o = o0 + t2*8;
            float acc = b1s[o];
            #pragma unroll
            for (int cc=0; cc<16; ++cc) acc += w1s[o*16+cc]*cat[cc];
            float sg = sigmoidf_(acc);
            if (isrow){ sh_s[o][pp]=sg; sh[bg*1024 + o*64 + pp]=sg; }
            else      { sw_s[o][pp]=sg; sw[bg*1024 + o*64 + pp]=sg; }
        }
    }
    __syncthreads();

    // ---- phase 3: instance-norm stats of x1 = x*sh_i*sw_j (x re-read is L3-hot) ----
    {
        int jb = (lane&15)*4;
        float sw0=sw_s[w][jb], sw1=sw_s[w][jb+1], sw2=sw_s[w][jb+2], sw3=sw_s[w][jb+3];
        float s1=0.f, s2=0.f;
        #pragma unroll
        for (int it=0; it<16; ++it){
            float4 v = xc4[it*64+lane];
            float si = sh_s[w][it*4+(lane>>4)];
            float a0=v.x*si*sw0, a1=v.y*si*sw1, a2=v.z*si*sw2, a3=v.w*si*sw3;
            s1 += a0+a1+a2+a3;
            s2 += a0*a0+a1*a1+a2*a2+a3*a3;
        }
        #pragma unroll
        for (int m=1;m<64;m<<=1){ s1+=__shfl_xor(s1,m); s2+=__shfl_xor(s2,m); }
        if (lane==0){
            float mu = s1*(1.0f/4096.0f);
            float var = s2*(1.0f/4096.0f) - mu*mu;
            mu_s[w]=mu; rstd_s[w]=rsqrtf(var+EPS);
        }
    }
    __syncthreads();

    // ---- phase 4: analytic mean(x2) -> a21 -> alpha, cst (all from LDS) ----
    if (tid < 144){
        int c = tid/9, k = tid - c*9, ky = k/3, kx = k - ky*3;
        float r = chs_s[c];
        if (ky==0) r -= rs_s[c][63];
        if (ky==2) r -= rs_s[c][0];
        if (kx==0) r -= cs_s[c][63];
        if (kx==2) r -= cs_s[c][0];
        if (ky!=1 && kx!=1) r += corn_s[c][((ky==0)?2:0)+((kx==0)?1:0)];
        regs[tid] = r;
    }
    __syncthreads();
    if (tid<16){
        float s=0.f;
        const float* wo = w3s + tid*144;
        for (int q=0;q<144;++q) s += wo[q]*regs[q];
        m2[tid] = b3[tid] + s*(1.0f/4096.0f);
    }
    __syncthreads();
    if (tid==0){
        float m = m2[0];
        for (int i=1;i<16;++i) m = fmaxf(m, m2[i]);
        float s=0.f, e[16];
        for (int i=0;i<16;++i){ e[i]=expf(m2[i]-m); s+=e[i]; }
        for (int i=0;i<16;++i) a21_s[i]=e[i]/s;
    }
    __syncthreads();
    if (tid<16){
        alpha[(bg<<4)+tid] = a21_s[tid]*gn_w[tid]*rstd_s[tid];
    }
    if (tid==0){
        float cv=0.f;
        for (int c2=0;c2<16;++c2)
            cv += a21_s[c2]*(gn_b[c2] - gn_w[c2]*rstd_s[c2]*mu_s[c2]);
        cst[bg]=cv;
    }
}

// ---------------- SE block for se1: 512 -> relu(32) -> sigmoid(512) ----------------
__global__ __launch_bounds__(512) void k_se(const float* __restrict__ pin, float scale,
    const float* __restrict__ wa, const float* __restrict__ ba,
    const float* __restrict__ wb, const float* __restrict__ bb,
    float* __restrict__ seout)
{
    int b = blockIdx.x, tid = threadIdx.x;
    __shared__ float pv[512];
    __shared__ float hdn[32];
    pv[tid] = pin[b*512+tid]*scale;
    __syncthreads();
    if (tid<32){
        float acc = ba[tid];
        const float* wr = wa + tid*512;
        for (int k=0;k<512;++k) acc += wr[k]*pv[k];
        hdn[tid] = fmaxf(acc, 0.0f);
    }
    __syncthreads();
    float acc = bb[tid];
    const float* wr = wb + tid*32;
    #pragma unroll
    for (int k=0;k<32;++k) acc += wr[k]*hdn[k];
    seout[b*512+tid] = sigmoidf_(acc);
}

// ---------------- SE block for se2: builds pin from p2part quarters + gamma*se1*chansum ----------------
__global__ __launch_bounds__(512) void k_se2(const float* __restrict__ p2part,
    const float* __restrict__ se1, const float* __restrict__ chansum,
    const float* __restrict__ gamma,
    const float* __restrict__ wa, const float* __restrict__ ba,
    const float* __restrict__ wb, const float* __restrict__ bb,
    float* __restrict__ seout)
{
    int b = blockIdx.x, tid = threadIdx.x;
    __shared__ float pv[512];
    __shared__ float hdn[32];
    int bg = b*32 + (tid>>4);
    int c  = tid & 15;
    float praw = p2part[(bg*4+0)*16 + c] + p2part[(bg*4+1)*16 + c]
               + p2part[(bg*4+2)*16 + c] + p2part[(bg*4+3)*16 + c];
    int bc = b*512 + tid;
    float g0 = gamma[0];
    pv[tid] = (praw + g0*se1[bc]*chansum[bc]) * (1.0f/4096.0f);
    __syncthreads();
    if (tid<32){
        float acc = ba[tid];
        const float* wr = wa + tid*512;
        for (int k=0;k<512;++k) acc += wr[k]*pv[k];
        hdn[tid] = fmaxf(acc, 0.0f);
    }
    __syncthreads();
    float acc = bb[tid];
    const float* wr = wb + tid*32;
    #pragma unroll
    for (int k=0;k<32;++k) acc += wr[k]*hdn[k];
    seout[b*512+tid] = sigmoidf_(acc);
}

// ---------------- K5: register-streaming conv + gating; sig=sigmoid(wv); psum from retained regs ----------------
// block = (bg, quarter); wave w handles 4-row stripe r0 = quarter*16 + w*4.
// Per channel: load 6 rows, retain 4 center rows in VGPRs; psum phase needs no re-read.
__global__ __launch_bounds__(256) void k5_wv(const float* __restrict__ x,
    const float* __restrict__ sh, const float* __restrict__ sw,
    const float* __restrict__ alpha, const float* __restrict__ cst,
    const float* __restrict__ weff, const float* __restrict__ bconst,
    float* __restrict__ sigbuf, float* __restrict__ p2part)
{
    const int bid = blockIdx.x;        // bg*4 + quarter
    const int bg  = bid >> 2;
    const int quarter = bid & 3;
    const int tid = threadIdx.x;
    const int j   = tid & 63;
    const int w   = tid >> 6;          // wave 0..3
    __shared__ float red[4][16];

    const int r0 = __builtin_amdgcn_readfirstlane(quarter*16 + w*4);
    const float* xb  = x + (size_t)bg*65536;    // [16][64][64]
    const float* shb = sh + bg*1024;
    const float* swb = sw + bg*1024;
    const float* alb = alpha + bg*16;
    const float cstv = cst[bg] + bconst[0];

    float A0[4], A1[4], A2[4], G[4];
    float keep[16][4];
    #pragma unroll
    for (int r=0;r<4;++r){ A0[r]=0.f; A1[r]=0.f; A2[r]=0.f; G[r]=0.f; }

    #pragma unroll
    for (int c=0;c<16;++c){
        const float* xc = xb + c*4096;
        const float* wq = weff + c*9;          // uniform -> s_loads
        float w0=wq[0], w1_=wq[1], w2=wq[2];
        float w3_=wq[3], w4=wq[4], w5=wq[5];
        float w6=wq[6], w7=wq[7], w8=wq[8];
        float alc = alb[c];
        float swv = swb[c*64 + j];
        float v[6];
        #pragma unroll
        for (int k=0;k<6;++k){
            int t = r0 - 1 + k;
            int tc = t < 0 ? 0 : (t > 63 ? 63 : t);
            float val = xc[tc*64 + j];
            v[k] = (t >= 0 && t < 64) ? val : 0.f;
        }
        #pragma unroll
        for (int r=0;r<4;++r) keep[c][r] = v[r+1];
        #pragma unroll
        for (int k=0;k<6;++k){
            if (k<=3){ A0[k]+=w0*v[k]; A1[k]+=w1_*v[k]; A2[k]+=w2*v[k]; }
            if (k>=1 && k<=4){
                A0[k-1]+=w3_*v[k]; A1[k-1]+=w4*v[k]; A2[k-1]+=w5*v[k];
                float u = alc * shb[c*64 + (r0+k-1)];   // uniform
                G[k-1] += u * (swv * v[k]);
            }
            if (k>=2){ A0[k-2]+=w6*v[k]; A1[k-2]+=w7*v[k]; A2[k-2]+=w8*v[k]; }
        }
    }

    float sg[4];
    #pragma unroll
    for (int r=0;r<4;++r){
        float l = __shfl_up(A0[r], 1);
        if (j==0) l = 0.f;
        float rr = __shfl_down(A2[r], 1);
        if (j==63) rr = 0.f;
        float s = sigmoidf_(l + A1[r] + rr + G[r] + cstv);
        sg[r] = s;
        sigbuf[bg*4096 + (r0+r)*64 + j] = s;
    }

    // psum partials from retained registers: sum_r keep[c][r]*sg[r]
    #pragma unroll
    for (int c=0;c<16;++c){
        float acc = keep[c][0]*sg[0] + keep[c][1]*sg[1]
                  + keep[c][2]*sg[2] + keep[c][3]*sg[3];
        #pragma unroll
        for (int m=1;m<64;m<<=1) acc += __shfl_xor(acc, m);
        if (j==0) red[w][c] = acc;
    }
    __syncthreads();
    if (tid<16){
        p2part[bid*16 + tid] = red[0][tid]+red[1][tid]+red[2][tid]+red[3][tid];
    }
}

// ---------------- K7: out = x * (sig + gamma*se1) * se2 ----------------
__global__ __launch_bounds__(256) void k7_out(const float* __restrict__ x,
    const float* __restrict__ sigbuf, const float* __restrict__ se1,
    const float* __restrict__ se2, const float* __restrict__ gamma,
    float* __restrict__ out)
{
    const floatx4* x4 = (const floatx4*)x;
    const floatx4* s4 = (const floatx4*)sigbuf;
    floatx4* o4 = (floatx4*)out;
    float g0 = gamma[0];
    int idx = blockIdx.x*256 + threadIdx.x;
    int stride = gridDim.x*256;
    for (int g4 = idx; g4 < 8388608; g4 += stride){
        int e = g4 << 2;
        int bC = e >> 12;
        int pix4 = g4 & 1023;
        int bg = bC >> 4;
        floatx4 xv = x4[g4];
        floatx4 sg = s4[bg*1024 + pix4];
        float f1 = g0*se1[bC];
        float s2v = se2[bC];
        floatx4 ov;
        ov.x = xv.x*(sg.x+f1)*s2v;
        ov.y = xv.y*(sg.y+f1)*s2v;
        ov.z = xv.z*(sg.z+f1)*s2v;
        ov.w = xv.w*(sg.w+f1)*s2v;
        __builtin_nontemporal_store(ov, &o4[g4]);
    }
}

extern "C" void kernel_launch(void* const* d_in, const int* in_sizes, int n_in,
                              void* d_out, int out_size, void* d_ws, size_t ws_size,
                              hipStream_t stream)
{
    const float* x     = (const float*)d_in[0];
    const float* w1    = (const float*)d_in[1];
    const float* b1    = (const float*)d_in[2];
    const float* w3    = (const float*)d_in[3];
    const float* b3    = (const float*)d_in[4];
    const float* gn_w  = (const float*)d_in[5];
    const float* gn_b  = (const float*)d_in[6];
    const float* cg_w1 = (const float*)d_in[7];
    const float* cg_b1 = (const float*)d_in[8];
    const float* cg_w2 = (const float*)d_in[9];
    const float* cg_b2 = (const float*)d_in[10];
    const float* ga_w1 = (const float*)d_in[11];
    const float* ga_b1 = (const float*)d_in[12];
    const float* ga_w2 = (const float*)d_in[13];
    const float* ga_b2 = (const float*)d_in[14];
    const float* gamma = (const float*)d_in[15];
    float* out = (float*)d_out;
    float* ws  = (float*)d_ws;

    // workspace layout (float offsets)
    float* sh      = ws + 0;         // 524288
    float* sw      = ws + 524288;    // 524288
    float* chansum = ws + 1048576;   // 8192
    float* alpha   = ws + 1056768;   // 8192
    float* cst     = ws + 1064960;   // 512
    float* weff    = ws + 1065472;   // 144
    float* bconst  = ws + 1065616;   // 1
    float* sigbuf  = ws + 1065728;   // 2097152 (16B aligned)
    float* p2part  = ws + 3162880;   // 32768 (2048 blocks * 16)
    float* se1     = ws + 3195648;   // 8192
    float* se2     = ws + 3203840;   // 8192

    k0_weff<<<1,256,0,stream>>>(w3, b3, gn_b, weff, bconst);
    kA<<<512,1024,0,stream>>>(x, w1, b1, w3, b3, gn_w, gn_b, sh, sw, chansum, alpha, cst);
    k_se<<<16,512,0,stream>>>(chansum, 1.0f/4096.0f, cg_w1, cg_b1, cg_w2, cg_b2, se1);
    k5_wv<<<2048,256,0,stream>>>(x, sh, sw, alpha, cst, weff, bconst, sigbuf, p2part);
    k_se2<<<16,512,0,stream>>>(p2part, se1, chansum, gamma, ga_w1, ga_b1, ga_w2, ga_b2, se2);
    k7_out<<<8192,256,0,stream>>>(x, sigbuf, se1, se2, gamma, out);
}

// Round 6
// 148.270 us; speedup vs baseline: 2.0577x; 1.1066x over previous
//
#include <hip/hip_runtime.h>
#include <math.h>

#define EPS 1e-5f

typedef float __attribute__((ext_vector_type(4))) floatx4;

__device__ __forceinline__ float sigmoidf_(float v){ return 1.0f/(1.0f+expf(-v)); }

// ---------------- KA: fused k0(weff)+k1(sums)+k2(gates)+k3(stats)+k4(a21/alpha/cst), one block per bg ----------------
__global__ __launch_bounds__(1024, 4) void kA(const float* __restrict__ x,
    const float* __restrict__ w1, const float* __restrict__ b1,
    const float* __restrict__ w3, const float* __restrict__ b3,
    const float* __restrict__ gn_w, const float* __restrict__ gn_b,
    float* __restrict__ sh, float* __restrict__ sw,
    float* __restrict__ chansum, float* __restrict__ alpha, float* __restrict__ cst,
    float* __restrict__ weff, float* __restrict__ bconst)
{
    const int bg = blockIdx.x;
    const int tid = threadIdx.x;
    const int w = tid >> 6;        // wave = channel 0..15
    const int lane = tid & 63;

    __shared__ float rs_s[16][64], cs_s[16][64];
    __shared__ float sh_s[16][64], sw_s[16][64];
    __shared__ float chs_s[16], corn_s[16][4], mu_s[16], rstd_s[16];
    __shared__ float w3s[2304], w1s[256], b1s[16];
    __shared__ float regs[144], m2[16], a21_s[16];

    for (int t=tid; t<2304; t+=1024) w3s[t] = w3[t];
    if (tid < 256) w1s[tid] = w1[tid];
    if (tid < 16)  b1s[tid] = b1[tid];

    const float4* xc4 = (const float4*)(x + (((size_t)bg<<4) + w)*4096);

    // ---- phase 1: row sums / col sums / total / corners; RETAIN x in VGPRs ----
    float4 xv[16];
    float c0=0.f,c1=0.f,c2=0.f,c3=0.f;
    #pragma unroll
    for (int it=0; it<16; ++it){
        float4 v = xc4[it*64 + lane];
        xv[it] = v;
        float rsum = v.x+v.y+v.z+v.w;
        rsum += __shfl_xor(rsum,1); rsum += __shfl_xor(rsum,2);
        rsum += __shfl_xor(rsum,4); rsum += __shfl_xor(rsum,8);
        if ((lane&15)==0) rs_s[w][it*4 + (lane>>4)] = rsum;
        c0+=v.x; c1+=v.y; c2+=v.z; c3+=v.w;
    }
    c0 += __shfl_xor(c0,16); c0 += __shfl_xor(c0,32);
    c1 += __shfl_xor(c1,16); c1 += __shfl_xor(c1,32);
    c2 += __shfl_xor(c2,16); c2 += __shfl_xor(c2,32);
    c3 += __shfl_xor(c3,16); c3 += __shfl_xor(c3,32);
    float tsum = c0+c1+c2+c3;
    tsum += __shfl_xor(tsum,1); tsum += __shfl_xor(tsum,2);
    tsum += __shfl_xor(tsum,4); tsum += __shfl_xor(tsum,8);
    if (lane < 16){
        cs_s[w][lane*4+0]=c0; cs_s[w][lane*4+1]=c1;
        cs_s[w][lane*4+2]=c2; cs_s[w][lane*4+3]=c3;
    }
    if (lane==0){
        chs_s[w]=tsum;
        chansum[(bg<<4)+w]=tsum;
        const float* xb = x + (((size_t)bg<<4)+w)*4096;
        corn_s[w][0]=xb[0]; corn_s[w][1]=xb[63];
        corn_s[w][2]=xb[4032]; corn_s[w][3]=xb[4095];
    }
    __syncthreads();

    // ---- phase 2: gates sh/sw (2048 dots of length 16; each thread does 2) ----
    {
        int p  = tid & 127;
        int o0 = tid >> 7;           // 0..7
        bool isrow = (p < 64);       // wave-uniform
        int pp = p & 63;
        float cat[16];
        #pragma unroll
        for (int cc=0; cc<16; ++cc)
            cat[cc] = (isrow ? rs_s[cc][pp] : cs_s[cc][pp]) * (1.0f/64.0f);
        #pragma unroll
        for (int t2=0; t2<2; ++t2){
            int o = o0 + t2*8;
            float acc = b1s[o];
            #pragma unroll
            for (int cc=0; cc<16; ++cc) acc += w1s[o*16+cc]*cat[cc];
            float sg = sigmoidf_(acc);
            if (isrow){ sh_s[o][pp]=sg; sh[bg*1024 + o*64 + pp]=sg; }
            else      { sw_s[o][pp]=sg; sw[bg*1024 + o*64 + pp]=sg; }
        }
    }
    __syncthreads();

    // ---- phase 3: instance-norm stats of x1 = x*sh_i*sw_j from RETAINED registers ----
    {
        int jb = (lane&15)*4;
        float sw0=sw_s[w][jb], sw1=sw_s[w][jb+1], sw2=sw_s[w][jb+2], sw3=sw_s[w][jb+3];
        float s1=0.f, s2=0.f;
        #pragma unroll
        for (int it=0; it<16; ++it){
            float4 v = xv[it];
            float si = sh_s[w][it*4+(lane>>4)];
            float a0=v.x*si*sw0, a1=v.y*si*sw1, a2=v.z*si*sw2, a3=v.w*si*sw3;
            s1 += a0+a1+a2+a3;
            s2 += a0*a0+a1*a1+a2*a2+a3*a3;
        }
        #pragma unroll
        for (int m=1;m<64;m<<=1){ s1+=__shfl_xor(s1,m); s2+=__shfl_xor(s2,m); }
        if (lane==0){
            float mu = s1*(1.0f/4096.0f);
            float var = s2*(1.0f/4096.0f) - mu*mu;
            mu_s[w]=mu; rstd_s[w]=rsqrtf(var+EPS);
        }
    }
    __syncthreads();

    // ---- phase 4: analytic mean(x2) -> a21 -> alpha, cst (all from LDS) ----
    if (tid < 144){
        int c = tid/9, k = tid - c*9, ky = k/3, kx = k - ky*3;
        float r = chs_s[c];
        if (ky==0) r -= rs_s[c][63];
        if (ky==2) r -= rs_s[c][0];
        if (kx==0) r -= cs_s[c][63];
        if (kx==2) r -= cs_s[c][0];
        if (ky!=1 && kx!=1) r += corn_s[c][((ky==0)?2:0)+((kx==0)?1:0)];
        regs[tid] = r;
    }
    __syncthreads();
    if (tid<16){
        float s=0.f;
        const float* wo = w3s + tid*144;
        for (int q=0;q<144;++q) s += wo[q]*regs[q];
        m2[tid] = b3[tid] + s*(1.0f/4096.0f);
    }
    __syncthreads();
    if (tid==0){
        float m = m2[0];
        for (int i=1;i<16;++i) m = fmaxf(m, m2[i]);
        float s=0.f, e[16];
        for (int i=0;i<16;++i){ e[i]=expf(m2[i]-m); s+=e[i]; }
        for (int i=0;i<16;++i) a21_s[i]=e[i]/s;
    }
    __syncthreads();
    if (tid<16){
        alpha[(bg<<4)+tid] = a21_s[tid]*gn_w[tid]*rstd_s[tid];
    }
    if (tid==0){
        float cv=0.f;
        for (int c2=0;c2<16;++c2)
            cv += a21_s[c2]*(gn_b[c2] - gn_w[c2]*rstd_s[c2]*mu_s[c2]);
        cst[bg]=cv;
    }

    // ---- folded k0 (bg==0 only): weff = sum_o a11[o]*w3[o], bconst = sum_o a11[o]*b3[o] ----
    if (bg==0 && tid<160){
        float a11[16];
        {
            float m = gn_b[0];
            #pragma unroll
            for (int i=1;i<16;++i) m = fmaxf(m, gn_b[i]);
            float s=0.f;
            #pragma unroll
            for (int i=0;i<16;++i){ a11[i]=expf(gn_b[i]-m); s+=a11[i]; }
            float inv = 1.0f/s;
            #pragma unroll
            for (int i=0;i<16;++i) a11[i]*=inv;
        }
        if (tid<144){
            float acc=0.f;
            #pragma unroll
            for (int o=0;o<16;++o) acc += a11[o]*w3s[o*144+tid];
            weff[tid]=acc;
        }
        if (tid==159){
            float acc=0.f;
            #pragma unroll
            for (int o=0;o<16;++o) acc += a11[o]*b3[o];
            bconst[0]=acc;
        }
    }
}

// ---------------- SE block for se1: 512 -> relu(32) -> sigmoid(512) ----------------
__global__ __launch_bounds__(512) void k_se(const float* __restrict__ pin, float scale,
    const float* __restrict__ wa, const float* __restrict__ ba,
    const float* __restrict__ wb, const float* __restrict__ bb,
    float* __restrict__ seout)
{
    int b = blockIdx.x, tid = threadIdx.x;
    __shared__ float pv[512];
    __shared__ float hdn[32];
    pv[tid] = pin[b*512+tid]*scale;
    __syncthreads();
    if (tid<32){
        float acc = ba[tid];
        const float* wr = wa + tid*512;
        for (int k=0;k<512;++k) acc += wr[k]*pv[k];
        hdn[tid] = fmaxf(acc, 0.0f);
    }
    __syncthreads();
    float acc = bb[tid];
    const float* wr = wb + tid*32;
    #pragma unroll
    for (int k=0;k<32;++k) acc += wr[k]*hdn[k];
    seout[b*512+tid] = sigmoidf_(acc);
}

// ---------------- SE block for se2: builds pin from p2part quarters + gamma*se1*chansum ----------------
__global__ __launch_bounds__(512) void k_se2(const float* __restrict__ p2part,
    const float* __restrict__ se1, const float* __restrict__ chansum,
    const float* __restrict__ gamma,
    const float* __restrict__ wa, const float* __restrict__ ba,
    const float* __restrict__ wb, const float* __restrict__ bb,
    float* __restrict__ seout)
{
    int b = blockIdx.x, tid = threadIdx.x;
    __shared__ float pv[512];
    __shared__ float hdn[32];
    int bg = b*32 + (tid>>4);
    int c  = tid & 15;
    float praw = p2part[(bg*4+0)*16 + c] + p2part[(bg*4+1)*16 + c]
               + p2part[(bg*4+2)*16 + c] + p2part[(bg*4+3)*16 + c];
    int bc = b*512 + tid;
    float g0 = gamma[0];
    pv[tid] = (praw + g0*se1[bc]*chansum[bc]) * (1.0f/4096.0f);
    __syncthreads();
    if (tid<32){
        float acc = ba[tid];
        const float* wr = wa + tid*512;
        for (int k=0;k<512;++k) acc += wr[k]*pv[k];
        hdn[tid] = fmaxf(acc, 0.0f);
    }
    __syncthreads();
    float acc = bb[tid];
    const float* wr = wb + tid*32;
    #pragma unroll
    for (int k=0;k<32;++k) acc += wr[k]*hdn[k];
    seout[b*512+tid] = sigmoidf_(acc);
}

// ---------------- K5: register-streaming conv + gating; sig=sigmoid(wv); psum from retained regs ----------------
// block = (bg, quarter); wave w handles 4-row stripe r0 = quarter*16 + w*4.
// Per channel: load 6 rows, retain 4 center rows in VGPRs; psum phase needs no re-read.
__global__ __launch_bounds__(256) void k5_wv(const float* __restrict__ x,
    const float* __restrict__ sh, const float* __restrict__ sw,
    const float* __restrict__ alpha, const float* __restrict__ cst,
    const float* __restrict__ weff, const float* __restrict__ bconst,
    float* __restrict__ sigbuf, float* __restrict__ p2part)
{
    const int bid = blockIdx.x;        // bg*4 + quarter
    const int bg  = bid >> 2;
    const int quarter = bid & 3;
    const int tid = threadIdx.x;
    const int j   = tid & 63;
    const int w   = tid >> 6;          // wave 0..3
    __shared__ float red[4][16];

    const int r0 = __builtin_amdgcn_readfirstlane(quarter*16 + w*4);
    const float* xb  = x + (size_t)bg*65536;    // [16][64][64]
    const float* shb = sh + bg*1024;
    const float* swb = sw + bg*1024;
    const float* alb = alpha + bg*16;
    const float cstv = cst[bg] + bconst[0];

    float A0[4], A1[4], A2[4], G[4];
    float keep[16][4];
    #pragma unroll
    for (int r=0;r<4;++r){ A0[r]=0.f; A1[r]=0.f; A2[r]=0.f; G[r]=0.f; }

    #pragma unroll
    for (int c=0;c<16;++c){
        const float* xc = xb + c*4096;
        const float* wq = weff + c*9;          // uniform -> s_loads
        float w0=wq[0], w1_=wq[1], w2=wq[2];
        float w3_=wq[3], w4=wq[4], w5=wq[5];
        float w6=wq[6], w7=wq[7], w8=wq[8];
        float alc = alb[c];
        float swv = swb[c*64 + j];
        float v[6];
        #pragma unroll
        for (int k=0;k<6;++k){
            int t = r0 - 1 + k;
            int tc = t < 0 ? 0 : (t > 63 ? 63 : t);
            float val = xc[tc*64 + j];
            v[k] = (t >= 0 && t < 64) ? val : 0.f;
        }
        #pragma unroll
        for (int r=0;r<4;++r) keep[c][r] = v[r+1];
        #pragma unroll
        for (int k=0;k<6;++k){
            if (k<=3){ A0[k]+=w0*v[k]; A1[k]+=w1_*v[k]; A2[k]+=w2*v[k]; }
            if (k>=1 && k<=4){
                A0[k-1]+=w3_*v[k]; A1[k-1]+=w4*v[k]; A2[k-1]+=w5*v[k];
                float u = alc * shb[c*64 + (r0+k-1)];   // uniform
                G[k-1] += u * (swv * v[k]);
            }
            if (k>=2){ A0[k-2]+=w6*v[k]; A1[k-2]+=w7*v[k]; A2[k-2]+=w8*v[k]; }
        }
    }

    float sg[4];
    #pragma unroll
    for (int r=0;r<4;++r){
        float l = __shfl_up(A0[r], 1);
        if (j==0) l = 0.f;
        float rr = __shfl_down(A2[r], 1);
        if (j==63) rr = 0.f;
        float s = sigmoidf_(l + A1[r] + rr + G[r] + cstv);
        sg[r] = s;
        sigbuf[bg*4096 + (r0+r)*64 + j] = s;
    }

    // psum partials from retained registers: sum_r keep[c][r]*sg[r]
    #pragma unroll
    for (int c=0;c<16;++c){
        float acc = keep[c][0]*sg[0] + keep[c][1]*sg[1]
                  + keep[c][2]*sg[2] + keep[c][3]*sg[3];
        #pragma unroll
        for (int m=1;m<64;m<<=1) acc += __shfl_xor(acc, m);
        if (j==0) red[w][c] = acc;
    }
    __syncthreads();
    if (tid<16){
        p2part[bid*16 + tid] = red[0][tid]+red[1][tid]+red[2][tid]+red[3][tid];
    }
}

// ---------------- K7: out = x * (sig + gamma*se1) * se2 ----------------
__global__ __launch_bounds__(256) void k7_out(const float* __restrict__ x,
    const float* __restrict__ sigbuf, const float* __restrict__ se1,
    const float* __restrict__ se2, const float* __restrict__ gamma,
    float* __restrict__ out)
{
    const floatx4* x4 = (const floatx4*)x;
    const floatx4* s4 = (const floatx4*)sigbuf;
    floatx4* o4 = (floatx4*)out;
    float g0 = gamma[0];
    int idx = blockIdx.x*256 + threadIdx.x;
    int stride = gridDim.x*256;
    for (int g4 = idx; g4 < 8388608; g4 += stride){
        int e = g4 << 2;
        int bC = e >> 12;
        int pix4 = g4 & 1023;
        int bg = bC >> 4;
        floatx4 xv = x4[g4];
        floatx4 sg = s4[bg*1024 + pix4];
        float f1 = g0*se1[bC];
        float s2v = se2[bC];
        floatx4 ov;
        ov.x = xv.x*(sg.x+f1)*s2v;
        ov.y = xv.y*(sg.y+f1)*s2v;
        ov.z = xv.z*(sg.z+f1)*s2v;
        ov.w = xv.w*(sg.w+f1)*s2v;
        __builtin_nontemporal_store(ov, &o4[g4]);
    }
}

extern "C" void kernel_launch(void* const* d_in, const int* in_sizes, int n_in,
                              void* d_out, int out_size, void* d_ws, size_t ws_size,
                              hipStream_t stream)
{
    const float* x     = (const float*)d_in[0];
    const float* w1    = (const float*)d_in[1];
    const float* b1    = (const float*)d_in[2];
    const float* w3    = (const float*)d_in[3];
    const float* b3    = (const float*)d_in[4];
    const float* gn_w  = (const float*)d_in[5];
    const float* gn_b  = (const float*)d_in[6];
    const float* cg_w1 = (const float*)d_in[7];
    const float* cg_b1 = (const float*)d_in[8];
    const float* cg_w2 = (const float*)d_in[9];
    const float* cg_b2 = (const float*)d_in[10];
    const float* ga_w1 = (const float*)d_in[11];
    const float* ga_b1 = (const float*)d_in[12];
    const float* ga_w2 = (const float*)d_in[13];
    const float* ga_b2 = (const float*)d_in[14];
    const float* gamma = (const float*)d_in[15];
    float* out = (float*)d_out;
    float* ws  = (float*)d_ws;

    // workspace layout (float offsets)
    float* sh      = ws + 0;         // 524288
    float* sw      = ws + 524288;    // 524288
    float* chansum = ws + 1048576;   // 8192
    float* alpha   = ws + 1056768;   // 8192
    float* cst     = ws + 1064960;   // 512
    float* weff    = ws + 1065472;   // 144
    float* bconst  = ws + 1065616;   // 1
    float* sigbuf  = ws + 1065728;   // 2097152 (16B aligned)
    float* p2part  = ws + 3162880;   // 32768 (2048 blocks * 16)
    float* se1     = ws + 3195648;   // 8192
    float* se2     = ws + 3203840;   // 8192

    kA<<<512,1024,0,stream>>>(x, w1, b1, w3, b3, gn_w, gn_b, sh, sw, chansum, alpha, cst, weff, bconst);
    k_se<<<16,512,0,stream>>>(chansum, 1.0f/4096.0f, cg_w1, cg_b1, cg_w2, cg_b2, se1);
    k5_wv<<<2048,256,0,stream>>>(x, sh, sw, alpha, cst, weff, bconst, sigbuf, p2part);
    k_se2<<<16,512,0,stream>>>(p2part, se1, chansum, gamma, ga_w1, ga_b1, ga_w2, ga_b2, se2);
    k7_out<<<8192,256,0,stream>>>(x, sigbuf, se1, se2, gamma, out);
}